// Round 9
// baseline (85.225 us; speedup 1.0000x reference)
//
#include <hip/hip_runtime.h>
#include <cstddef>
#include <cstdint>

#define EPS 1e-5f

typedef __bf16 bf16x8 __attribute__((ext_vector_type(8)));
typedef float f32x4 __attribute__((ext_vector_type(4)));
typedef unsigned short u16x8 __attribute__((ext_vector_type(8)));

__device__ __forceinline__ unsigned short f2bf(float f) {
  unsigned u = __builtin_bit_cast(unsigned, f);
  unsigned r = u + 0x7FFFu + ((u >> 16) & 1u);
  return (unsigned short)(r >> 16);
}
__device__ __forceinline__ float bf2f(unsigned short h) {
  unsigned u = (unsigned)h << 16;
  return __builtin_bit_cast(float, u);
}

__device__ __forceinline__ void gl_lds16(const void* g, void* l) {
  __builtin_amdgcn_global_load_lds(
      (const __attribute__((address_space(1))) unsigned int*)g,
      (__attribute__((address_space(3))) unsigned int*)l, 16, 0, 0);
}

// =============== bf16 MFMA GEMM: 4 waves, 128x128 tile, BK=64, dbuf + counted vmcnt ===============
// (round-7 proven structure: 64x64 per wave, 32 MFMA : 16 ds_read_b128 per K-step)
// MODE 0: merged q/k (N=2048, bias/gamma selected by col>>10)
// MODE 1: p-branch, per-batch early return (no Y write, no stats for skipped batches)
// MODE 2: v-branch, whole-kernel skip when flags[0]==0
template <int MODE, int NX>
__global__ __launch_bounds__(256) void gemm4_bf16_bt(
    const unsigned short* __restrict__ A, const unsigned short* __restrict__ Bmat,
    const float* __restrict__ b0, const float* __restrict__ b1,
    unsigned short* __restrict__ Y, double* __restrict__ psum, double* __restrict__ psq,
    const int* __restrict__ flags, int N, int Kc)
{
  if (MODE == 2) { if (flags[0] == 0) return; }

  __shared__ unsigned short As[2][8192];   // 2 x 16 KB
  __shared__ unsigned short Bs[2][8192];   // 2 x 16 KB
  const int tid = threadIdx.x;

  // XCD-chunked swizzle (bijective: nwg = NX*32 divisible by 8)
  constexpr int NXL = (NX == 16) ? 4 : 3;
  const int bid = blockIdx.x + (blockIdx.y << NXL);
  const int cpx = (NX * 32) >> 3;
  const int sw = (bid & 7) * cpx + (bid >> 3);
  const int bx = sw & (NX - 1), by = sw >> NXL;

  if (MODE == 1) { if (flags[1 + (by >> 3)] == 0) return; }

  const int bm = by * 128, bn = bx * 128;
  const int lane = tid & 63, w = tid >> 6;
  const int wr = w >> 1, wc = w & 1;            // 2x2 waves, 64x64 per wave
  const int l15 = lane & 15, g = lane >> 4;

  f32x4 acc[4][4] = {};

  const unsigned short* aSrc[4]; const unsigned short* bSrc[4]; int dOff[4];
#pragma unroll
  for (int c = 0; c < 4; ++c) {
    int S = c * 256 + tid;
    int row = S >> 3, sp = S & 7;
    int sl = sp ^ (row & 7);
    aSrc[c] = A    + (size_t)(bm + row) * Kc + sl * 8;
    bSrc[c] = Bmat + (size_t)(bn + row) * Kc + sl * 8;
    dOff[c] = S * 8;
  }
  int aOff[4][2], bOff[4][2];
#pragma unroll
  for (int i = 0; i < 4; ++i)
#pragma unroll
    for (int t = 0; t < 2; ++t) {
      int rowA = wr * 64 + i * 16 + l15;
      aOff[i][t] = rowA * 64 + ((t * 4 + g) ^ (rowA & 7)) * 8;
      int rowB = wc * 64 + i * 16 + l15;
      bOff[i][t] = rowB * 64 + ((t * 4 + g) ^ (rowB & 7)) * 8;
    }

  const int nk = Kc >> 6;
  // prologue: stage tile 0 (8 gl_lds per thread)
#pragma unroll
  for (int c = 0; c < 4; ++c) { gl_lds16(aSrc[c], &As[0][dOff[c]]); aSrc[c] += 64; }
#pragma unroll
  for (int c = 0; c < 4; ++c) { gl_lds16(bSrc[c], &Bs[0][dOff[c]]); bSrc[c] += 64; }

  int cur = 0;
  for (int kt = 0; kt < nk; ++kt) {
    if (kt + 1 < nk) {
#pragma unroll
      for (int c = 0; c < 4; ++c) { gl_lds16(aSrc[c], &As[cur ^ 1][dOff[c]]); aSrc[c] += 64; }
#pragma unroll
      for (int c = 0; c < 4; ++c) { gl_lds16(bSrc[c], &Bs[cur ^ 1][dOff[c]]); bSrc[c] += 64; }
      asm volatile("s_waitcnt vmcnt(8)" ::: "memory");   // tile kt landed; next stays in flight
    } else {
      asm volatile("s_waitcnt vmcnt(0)" ::: "memory");
    }
    __builtin_amdgcn_s_barrier();
    __builtin_amdgcn_sched_barrier(0);
    {
      const unsigned short* Ac = &As[cur][0];
      const unsigned short* Bc = &Bs[cur][0];
#pragma unroll
      for (int t = 0; t < 2; ++t) {
        bf16x8 af[4], bfr[4];
#pragma unroll
        for (int i = 0; i < 4; ++i) af[i] = *(const bf16x8*)&Ac[aOff[i][t]];
#pragma unroll
        for (int j = 0; j < 4; ++j) bfr[j] = *(const bf16x8*)&Bc[bOff[j][t]];
#pragma unroll
        for (int i = 0; i < 4; ++i)
#pragma unroll
          for (int j = 0; j < 4; ++j)
            acc[i][j] = __builtin_amdgcn_mfma_f32_16x16x32_bf16(af[i], bfr[j], acc[i][j], 0, 0, 0);
      }
    }
    __builtin_amdgcn_s_barrier();
    cur ^= 1;
  }

  // ---- epilogue: bf16 store + per-column partials (of stored values) ----
  const int r0 = bm + wr * 64 + g * 4;
  float csum[4], csq[4];
#pragma unroll
  for (int j = 0; j < 4; ++j) { csum[j] = 0.f; csq[j] = 0.f; }
#pragma unroll
  for (int j = 0; j < 4; ++j) {
    int col = bn + wc * 64 + j * 16 + l15;
    float bv = (MODE == 0) ? ((col >> 10) ? b1[col & 1023] : b0[col]) : b0[col];
#pragma unroll
    for (int i = 0; i < 4; ++i)
#pragma unroll
      for (int r = 0; r < 4; ++r) {
        float yv = acc[i][j][r] + bv;
        unsigned short h = f2bf(yv);
        float yb = bf2f(h);
        Y[(size_t)(r0 + i * 16 + r) * N + col] = h;
        csum[j] += yb;
        csq[j] += yb * yb;
      }
  }
  __syncthreads();
  float* Ls = (float*)&As[0][0];                 // 8 slots x 128 cols, sums then sqs
  const int slot = wr * 4 + g;
#pragma unroll
  for (int j = 0; j < 4; ++j) {
    int ci = wc * 64 + j * 16 + l15;
    Ls[slot * 128 + ci] = csum[j];
    Ls[1024 + slot * 128 + ci] = csq[j];
  }
  __syncthreads();
  if (tid < 128) {
    double s = 0.0, q = 0.0;
#pragma unroll
    for (int sl = 0; sl < 8; ++sl) {
      s += (double)Ls[sl * 128 + tid];
      q += (double)Ls[1024 + sl * 128 + tid];
    }
    size_t o = (size_t)by * N + bn + tid;
    psum[o] = s;
    psq[o] = q;
  }
}

// =============== prep1: x, Wq, Wk converts (always needed) ===============
__global__ void prep1_kernel(const float* __restrict__ x,
                             const float* __restrict__ Wq, const float* __restrict__ Wk,
                             unsigned short* __restrict__ Xh, unsigned short* __restrict__ Wh3)
{
  int bid = blockIdx.x, tid = threadIdx.x;
  const float* src; unsigned short* dst; size_t base;
  if (bid < 2048) {
    src = x; dst = Xh; base = ((size_t)bid * 256 + tid) * 8;
  } else if (bid < 2560) {
    src = Wq; dst = Wh3; base = ((size_t)(bid - 2048) * 256 + tid) * 8;
  } else {
    src = Wk; dst = Wh3 + (size_t)1024 * 1024; base = ((size_t)(bid - 2560) * 256 + tid) * 8;
  }
  float4 a = *reinterpret_cast<const float4*>(&src[base]);
  float4 b = *reinterpret_cast<const float4*>(&src[base + 4]);
  u16x8 o;
  o[0] = f2bf(a.x); o[1] = f2bf(a.y); o[2] = f2bf(a.z); o[3] = f2bf(a.w);
  o[4] = f2bf(b.x); o[5] = f2bf(b.y); o[6] = f2bf(b.z); o[7] = f2bf(b.w);
  *reinterpret_cast<u16x8*>(&dst[base]) = o;
}

// =============== prep2: Wv convert + Wp [hi|lo] split (gate-guarded) ===============
__global__ void prep2_kernel(const float* __restrict__ Wv, const float* __restrict__ Wp,
                             unsigned short* __restrict__ Whv, unsigned short* __restrict__ Wpcat,
                             const int* __restrict__ flags)
{
  if (flags[0] == 0) return;
  int bid = blockIdx.x, tid = threadIdx.x;
  if (bid < 512) {
    size_t base = ((size_t)bid * 256 + tid) * 8;
    float4 a = *reinterpret_cast<const float4*>(&Wv[base]);
    float4 b = *reinterpret_cast<const float4*>(&Wv[base + 4]);
    u16x8 o;
    o[0] = f2bf(a.x); o[1] = f2bf(a.y); o[2] = f2bf(a.z); o[3] = f2bf(a.w);
    o[4] = f2bf(b.x); o[5] = f2bf(b.y); o[6] = f2bf(b.z); o[7] = f2bf(b.w);
    *reinterpret_cast<u16x8*>(&Whv[base]) = o;
  } else {
    size_t base = ((size_t)(bid - 512) * 256 + tid) * 8;
    int r = (int)(base >> 10), c = (int)(base & 1023);
    float4 a = *reinterpret_cast<const float4*>(&Wp[base]);
    float4 b = *reinterpret_cast<const float4*>(&Wp[base + 4]);
    u16x8 hi, lo;
    hi[0] = f2bf(a.x); lo[0] = f2bf(a.x - bf2f(hi[0]));
    hi[1] = f2bf(a.y); lo[1] = f2bf(a.y - bf2f(hi[1]));
    hi[2] = f2bf(a.z); lo[2] = f2bf(a.z - bf2f(hi[2]));
    hi[3] = f2bf(a.w); lo[3] = f2bf(a.w - bf2f(hi[3]));
    hi[4] = f2bf(b.x); lo[4] = f2bf(b.x - bf2f(hi[4]));
    hi[5] = f2bf(b.y); lo[5] = f2bf(b.y - bf2f(hi[5]));
    hi[6] = f2bf(b.z); lo[6] = f2bf(b.z - bf2f(hi[6]));
    hi[7] = f2bf(b.w); lo[7] = f2bf(b.w - bf2f(hi[7]));
    unsigned short* Or = Wpcat + (size_t)r * 2048;
    *reinterpret_cast<u16x8*>(&Or[c]) = hi;
    *reinterpret_cast<u16x8*>(&Or[1024 + c]) = lo;
  }
}

// =============== BN finalize merged q/k (2048 cols); zeroes flags+energy ===============
__global__ void bn_finalize_qk(const double* __restrict__ psum, const double* __restrict__ psq,
                               const float* __restrict__ gq, const float* __restrict__ gk,
                               float* __restrict__ meanv, float* __restrict__ Av,
                               int* __restrict__ zflags, int* __restrict__ zenergy,
                               double invM)
{
  if (blockIdx.x == 0) {
    int t = threadIdx.x;
    if (t < 5) zflags[t] = 0;
    if (t >= 64 && t < 128) zenergy[t - 64] = 0;
  }
  int c = blockIdx.x * blockDim.x + threadIdx.x;     // 0..2047
  const double* ps = psum + c;
  const double* pq = psq + c;
  double s0 = 0, s1 = 0, q0 = 0, q1 = 0;
#pragma unroll
  for (int rb = 0; rb < 32; rb += 2) {
    s0 += ps[(size_t)rb * 2048];       q0 += pq[(size_t)rb * 2048];
    s1 += ps[(size_t)(rb + 1) * 2048]; q1 += pq[(size_t)(rb + 1) * 2048];
  }
  double s = s0 + s1, q = q0 + q1;
  double m = s * invM;
  double var = q * invM - m * m;
  if (var < 0.0) var = 0.0;
  float gv = (c >> 10) ? gk[c & 1023] : gq[c];
  meanv[c] = (float)m;
  Av[c] = gv * rsqrtf((float)var + EPS);
}

// =============== BN finalize v (1024 cols, runflag) ===============
__global__ void bn_finalize_v(const double* __restrict__ psum, const double* __restrict__ psq,
                              const float* __restrict__ gv,
                              float* __restrict__ meanv, float* __restrict__ Av,
                              const int* __restrict__ runflag, double invM)
{
  if (runflag[0] == 0) return;
  int c = blockIdx.x * blockDim.x + threadIdx.x;
  const double* ps = psum + c;
  const double* pq = psq + c;
  double s0 = 0, s1 = 0, q0 = 0, q1 = 0;
#pragma unroll
  for (int rb = 0; rb < 32; rb += 2) {
    s0 += ps[(size_t)rb * 1024];       q0 += pq[(size_t)rb * 1024];
    s1 += ps[(size_t)(rb + 1) * 1024]; q1 += pq[(size_t)(rb + 1) * 1024];
  }
  double s = s0 + s1, q = q0 + q1;
  double m = s * invM;
  double var = q * invM - m * m;
  if (var < 0.0) var = 0.0;
  meanv[c] = (float)m;
  Av[c] = gv[(size_t)c] * rsqrtf((float)var + EPS);
}

// =============== BN finalize p: analytic contribution for gated-off batches ===============
__global__ void bn_finalize_p(const double* __restrict__ psum, const double* __restrict__ psq,
                              const float* __restrict__ gp, const float* __restrict__ bp,
                              float* __restrict__ meanv, float* __restrict__ Av,
                              const int* __restrict__ flags, double invM)
{
  int c = blockIdx.x * blockDim.x + threadIdx.x;
  float ybb = bf2f(f2bf(bp[c]));
  double yd = (double)ybb;
  double s = 0.0, q = 0.0;
  for (int rb = 0; rb < 32; ++rb) {
    if (flags[1 + (rb >> 3)]) {
      s += psum[(size_t)rb * 1024 + c];
      q += psq [(size_t)rb * 1024 + c];
    } else {
      s += 128.0 * yd;
      q += 128.0 * yd * yd;
    }
  }
  double m = s * invM;
  double var = q * invM - m * m;
  if (var < 0.0) var = 0.0;
  meanv[c] = (float)m;
  Av[c] = gp[(size_t)c] * rsqrtf((float)var + EPS);
}

// =============== energy count only (interleaved Yqk [4096][2048]) ===============
__global__ void energy_cnt(const unsigned short* __restrict__ Yqk,
                           const float* __restrict__ meanv, const float* __restrict__ Av,
                           const float* __restrict__ beq, const float* __restrict__ bek,
                           int* __restrict__ energy_int)
{
  const int tid = threadIdx.x;
  const int half = tid >> 7;              // 2 rows processed per iter
  const int tloc = tid & 127;
  const int c0 = tloc * 8;
  const int head = c0 >> 6;
  const int r0 = blockIdx.x * 8;
  const int batch = blockIdx.x >> 7;      // 128 blocks per batch
  const float* mq = meanv;        const float* aq = Av;
  const float* mk = meanv + 1024; const float* ak = Av + 1024;
  __shared__ int bins[16];
  if (tid < 16) bins[tid] = 0;
  __syncthreads();
  int cnt = 0;
#pragma unroll
  for (int j = 0; j < 4; ++j) {
    int row = r0 + j * 2 + half;
    size_t base = (size_t)row * 2048 + c0;
    u16x8 yq = *reinterpret_cast<const u16x8*>(&Yqk[base]);
    u16x8 yk = *reinterpret_cast<const u16x8*>(&Yqk[base + 1024]);
#pragma unroll
    for (int e = 0; e < 8; ++e) {
      bool sq = (bf2f(yq[e]) - mq[c0 + e]) * aq[c0 + e] + beq[c0 + e] >= 2.0f;
      bool sk = (bf2f(yk[e]) - mk[c0 + e]) * ak[c0 + e] + bek[c0 + e] >= 2.0f;
      cnt += (sq && sk) ? 1 : 0;
    }
  }
  atomicAdd(&bins[head], cnt);
  __syncthreads();
  if (tid < 16) atomicAdd(&energy_int[batch * 16 + tid], bins[tid]);
}

// =============== q/k spike write (gate-guarded) ===============
__global__ void spike_qk_write(const unsigned short* __restrict__ Yqk,
                               const float* __restrict__ meanv, const float* __restrict__ Av,
                               const float* __restrict__ beq, const float* __restrict__ bek,
                               unsigned short* __restrict__ qb, unsigned short* __restrict__ kb,
                               const int* __restrict__ flags)
{
  if (flags[0] == 0) return;
  int idx = blockIdx.x * 256 + threadIdx.x;        // 4096*128 positions
  int r = idx >> 7, c0 = (idx & 127) * 8;
  const float* mq = meanv;        const float* aq = Av;
  const float* mk = meanv + 1024; const float* ak = Av + 1024;
  size_t src = (size_t)r * 2048 + c0;
  u16x8 yq = *reinterpret_cast<const u16x8*>(&Yqk[src]);
  u16x8 yk = *reinterpret_cast<const u16x8*>(&Yqk[src + 1024]);
  u16x8 oq, ok;
#pragma unroll
  for (int e = 0; e < 8; ++e) {
    oq[e] = ((bf2f(yq[e]) - mq[c0 + e]) * aq[c0 + e] + beq[c0 + e] >= 2.0f) ? 0x3F80 : 0;
    ok[e] = ((bf2f(yk[e]) - mk[c0 + e]) * ak[c0 + e] + bek[c0 + e] >= 2.0f) ? 0x3F80 : 0;
  }
  size_t dst = (size_t)r * 1024 + c0;
  *reinterpret_cast<u16x8*>(&qb[dst]) = oq;
  *reinterpret_cast<u16x8*>(&kb[dst]) = ok;
}

// =============== v spike (flag-guarded) ===============
__global__ void spike_v(const unsigned short* __restrict__ Yv,
                        const float* __restrict__ meanv, const float* __restrict__ Av,
                        const float* __restrict__ beta, unsigned short* __restrict__ vb,
                        const int* __restrict__ flags, int N)
{
  if (flags[0] == 0) return;
  size_t base = ((size_t)blockIdx.x * 256 + threadIdx.x) * 8;
  int c0 = (int)(base & (size_t)(N - 1));
  u16x8 y8 = *reinterpret_cast<const u16x8*>(&Yv[base]);
  u16x8 o;
#pragma unroll
  for (int e = 0; e < 8; ++e)
    o[e] = ((bf2f(y8[e]) - meanv[c0 + e]) * Av[c0 + e] + beta[c0 + e] >= 2.0f) ? 0x3F80 : 0;
  *reinterpret_cast<u16x8*>(&vb[base]) = o;
}

// =============== final output spike (flag-aware) ===============
__global__ void bn_spike_f32(const unsigned short* __restrict__ Y,
                             const float* __restrict__ meanv, const float* __restrict__ Av,
                             const float* __restrict__ beta, const float* __restrict__ bp,
                             const int* __restrict__ flags, float* __restrict__ S, int N)
{
  size_t base = ((size_t)blockIdx.x * 256 + threadIdx.x) * 8;
  int c0 = (int)(base & (size_t)(N - 1));
  int batch = (int)(base >> 20);
  float y[8];
  if (flags[1 + batch]) {
    u16x8 y8 = *reinterpret_cast<const u16x8*>(&Y[base]);
#pragma unroll
    for (int e = 0; e < 8; ++e) y[e] = bf2f(y8[e]);
  } else {
#pragma unroll
    for (int e = 0; e < 8; ++e) y[e] = bf2f(f2bf(bp[c0 + e]));
  }
  float4 o0, o1;
  o0.x = ((y[0] - meanv[c0 + 0]) * Av[c0 + 0] + beta[c0 + 0] >= 2.0f) ? 1.f : 0.f;
  o0.y = ((y[1] - meanv[c0 + 1]) * Av[c0 + 1] + beta[c0 + 1] >= 2.0f) ? 1.f : 0.f;
  o0.z = ((y[2] - meanv[c0 + 2]) * Av[c0 + 2] + beta[c0 + 2] >= 2.0f) ? 1.f : 0.f;
  o0.w = ((y[3] - meanv[c0 + 3]) * Av[c0 + 3] + beta[c0 + 3] >= 2.0f) ? 1.f : 0.f;
  o1.x = ((y[4] - meanv[c0 + 4]) * Av[c0 + 4] + beta[c0 + 4] >= 2.0f) ? 1.f : 0.f;
  o1.y = ((y[5] - meanv[c0 + 5]) * Av[c0 + 5] + beta[c0 + 5] >= 2.0f) ? 1.f : 0.f;
  o1.z = ((y[6] - meanv[c0 + 6]) * Av[c0 + 6] + beta[c0 + 6] >= 2.0f) ? 1.f : 0.f;
  o1.w = ((y[7] - meanv[c0 + 7]) * Av[c0 + 7] + beta[c0 + 7] >= 2.0f) ? 1.f : 0.f;
  *reinterpret_cast<float4*>(&S[base]) = o0;
  *reinterpret_cast<float4*>(&S[base + 4]) = o1;
}

// =============== gate ===============
__global__ void gate_kernel(const int* __restrict__ energy_int, const float* __restrict__ Wg,
                            const float* __restrict__ bg, float* __restrict__ gate,
                            int* __restrict__ flags, int D)
{
  int b = blockIdx.x >> 4, hp = blockIdx.x & 15;
  int tid = threadIdx.x;
  float e[16];
#pragma unroll
  for (int h = 0; h < 16; ++h) e[h] = (float)energy_int[b * 16 + h] * (1.f / 1024.f);
  float s = 0.f;
  for (int j = tid; j < D; j += 256) s = fmaf(e[j & 15], Wg[(size_t)hp * D + j], s);
  __shared__ float red[256];
  red[tid] = s;
  __syncthreads();
  for (int off = 128; off; off >>= 1) {
    if (tid < off) red[tid] += red[tid + off];
    __syncthreads();
  }
  if (tid == 0) {
    int gv = (red[0] + bg[hp] >= 0.5f) ? 1 : 0;
    gate[blockIdx.x] = (float)gv;
    if (gv) { atomicOr(&flags[0], 1); atomicOr(&flags[1 + b], 1); }
  }
}

// =============== gated attention + spike -> xat2 bf16 [4096][2048]=[s|s] ===============
__global__ __launch_bounds__(256) void attn_kernel(
    const unsigned short* __restrict__ qb, const unsigned short* __restrict__ kb,
    const unsigned short* __restrict__ vb, const float* __restrict__ gate,
    const int* __restrict__ flags, unsigned short* __restrict__ xs,
    int Ntok, int D, float scale)
{
  int bh = blockIdx.x;
  int b = bh >> 4, h = bh & 15;
  if (flags[1 + b] == 0) return;
  int n0 = blockIdx.y * 32;
  int tid = threadIdx.x;
  unsigned short* outbase = xs + (size_t)(b * Ntok + n0) * 2048 + h * 64;

  if (gate[bh] == 0.f) {
    ushort4 zv = {0, 0, 0, 0};
    for (int i = tid; i < 32 * 16; i += 256) {
      int r = i >> 4, c4 = (i & 15) << 2;
      *reinterpret_cast<ushort4*>(&outbase[(size_t)r * 2048 + c4]) = zv;
      *reinterpret_cast<ushort4*>(&outbase[(size_t)r * 2048 + 1024 + c4]) = zv;
    }
    return;
  }

  __shared__ float qs[32][68], ks[32][68], vs[32][68], Ss[32][36];
  const unsigned short* qg = qb + (size_t)b * Ntok * D + h * 64;
  const unsigned short* kg = kb + (size_t)b * Ntok * D + h * 64;
  const unsigned short* vg = vb + (size_t)b * Ntok * D + h * 64;

  {
    int r = tid >> 3, c8 = (tid & 7) * 8;
    u16x8 t = *reinterpret_cast<const u16x8*>(&qg[(size_t)(n0 + r) * D + c8]);
#pragma unroll
    for (int e = 0; e < 8; ++e) qs[r][c8 + e] = bf2f(t[e]);
  }

  float acc[8];
#pragma unroll
  for (int j = 0; j < 8; ++j) acc[j] = 0.f;
  const int nloc = tid >> 3;
  const int dd0 = (tid & 7) * 8;

  for (int mt = 0; mt < Ntok / 32; ++mt) {
    int m0 = mt * 32;
    __syncthreads();
    {
      int r = tid >> 3, c8 = (tid & 7) * 8;
      u16x8 tk = *reinterpret_cast<const u16x8*>(&kg[(size_t)(m0 + r) * D + c8]);
      u16x8 tv = *reinterpret_cast<const u16x8*>(&vg[(size_t)(m0 + r) * D + c8]);
#pragma unroll
      for (int e = 0; e < 8; ++e) { ks[r][c8 + e] = bf2f(tk[e]); vs[r][c8 + e] = bf2f(tv[e]); }
    }
    __syncthreads();
    {
      int np = tid >> 3;
      int mp0 = (tid & 7) * 4;
      float s0 = 0.f, s1 = 0.f, s2 = 0.f, s3 = 0.f;
#pragma unroll 8
      for (int d = 0; d < 64; ++d) {
        float qv = qs[np][d];
        s0 = fmaf(qv, ks[mp0 + 0][d], s0);
        s1 = fmaf(qv, ks[mp0 + 1][d], s1);
        s2 = fmaf(qv, ks[mp0 + 2][d], s2);
        s3 = fmaf(qv, ks[mp0 + 3][d], s3);
      }
      Ss[np][mp0 + 0] = s0; Ss[np][mp0 + 1] = s1;
      Ss[np][mp0 + 2] = s2; Ss[np][mp0 + 3] = s3;
    }
    __syncthreads();
#pragma unroll 8
    for (int mp = 0; mp < 32; ++mp) {
      float sv = Ss[nloc][mp];
#pragma unroll
      for (int j = 0; j < 8; ++j) acc[j] = fmaf(sv, vs[mp][dd0 + j], acc[j]);
    }
  }

#pragma unroll
  for (int j = 0; j < 8; ++j) {
    float x = scale * acc[j];
    unsigned short sp = (x >= 1.0f) ? 0x3F80 : 0;
    outbase[(size_t)nloc * 2048 + dd0 + j] = sp;
    outbase[(size_t)nloc * 2048 + 1024 + dd0 + j] = sp;
  }
}

// ======================================================================
extern "C" void kernel_launch(void* const* d_in, const int* in_sizes, int n_in,
                              void* d_out, int out_size, void* d_ws, size_t ws_size,
                              hipStream_t stream)
{
  (void)in_sizes; (void)n_in; (void)out_size; (void)ws_size;
  const int Ntok = 1024, D = 1024;
  const int M = 4096;
  const float scale = 0.5946035575013605f;      // 64^(-1/8)

  const float* x     = (const float*)d_in[0];
  const float* Wq    = (const float*)d_in[1];
  const float* bq    = (const float*)d_in[2];
  const float* gq    = (const float*)d_in[3];
  const float* betaq = (const float*)d_in[4];
  const float* Wk    = (const float*)d_in[5];
  const float* bk    = (const float*)d_in[6];
  const float* gk    = (const float*)d_in[7];
  const float* betak = (const float*)d_in[8];
  const float* Wv    = (const float*)d_in[9];
  const float* bv    = (const float*)d_in[10];
  const float* gv    = (const float*)d_in[11];
  const float* betav = (const float*)d_in[12];
  const float* Wp    = (const float*)d_in[13];
  const float* bp    = (const float*)d_in[14];
  const float* gp    = (const float*)d_in[15];
  const float* betap = (const float*)d_in[16];
  const float* Wg    = (const float*)d_in[17];
  const float* bg    = (const float*)d_in[18];

  char* w = (char*)d_ws;
  const size_t MB = 1024 * 1024;
  const size_t MN = (size_t)M * D;
  unsigned short* Yqk   = (unsigned short*)(w + 0 * MB);    // 16 MB [4096][2048] interleaved
  unsigned short* xat2  = (unsigned short*)(w + 0 * MB);    // alias (Yqk dead after spike_qk)
  unsigned short* Yv    = (unsigned short*)(w + 16 * MB);   // 8 MB
  unsigned short* Yp    = (unsigned short*)(w + 24 * MB);   // 8 MB
  unsigned short* Wpcat = (unsigned short*)(w + 32 * MB);   // 4 MB
  unsigned short* Xh    = (unsigned short*)(w + 48 * MB);   // 8 MB
  unsigned short* Wh3   = (unsigned short*)(w + 56 * MB);   // 6 MB: [Wq;Wk] stacked + Wv
  unsigned short* qb2   = (unsigned short*)(w + 62 * MB);   // 8 MB
  unsigned short* kb2   = (unsigned short*)(w + 70 * MB);   // 8 MB
  unsigned short* vb2   = (unsigned short*)(w + 78 * MB);   // 8 MB
  double* psum_qk = (double*)(w + 86 * MB);                 // [32][2048] 512 KB (p reuses)
  double* psq_qk  = (double*)(w + 86 * MB + 524288);        // 512 KB
  double* psum_v  = (double*)(w + 87 * MB);                 // [32][1024] 256 KB
  double* psq_v   = (double*)(w + 87 * MB + 262144);        // 256 KB
  float*  meanv  = (float*)(w + 88 * MB);                   // [q|k](2048) + v(1024) + p(1024)
  float*  Av     = (float*)(w + 88 * MB + 16384);
  int*    energy_int = (int*)(w + 88 * MB + 32768);
  int*    flags  = (int*)(w + 88 * MB + 32768 + 512);       // [any, batch0..3]
  float*  gate   = (float*)(w + 88 * MB + 32768 + 1024);

  float* out = (float*)d_out;
  unsigned short* Whqk = Wh3;                  // [2048][1024] stacked
  unsigned short* Whv  = Wh3 + 2 * (size_t)D * D;
  float* meanvv = meanv + 2 * D;  float* Avv = Av + 2 * D;
  float* meanp  = meanv + 3 * D;  float* Avp = Av + 3 * D;

  // ---- converts (always-needed) ----
  prep1_kernel<<<dim3(3072), 256, 0, stream>>>(x, Wq, Wk, Xh, Wh3);

  // ---- merged q,k GEMM (+fused stats), N=2048 ----
  gemm4_bf16_bt<0, 16><<<dim3(16, 32, 1), 256, 0, stream>>>(
      Xh, Whqk, bq, bk, Yqk, psum_qk, psq_qk, nullptr, 2048, 1024);
  bn_finalize_qk<<<dim3(8), 256, 0, stream>>>(
      psum_qk, psq_qk, gq, gk, meanv, Av, flags, energy_int, 1.0 / M);

  // ---- energy (count-only) + gate ----
  energy_cnt<<<dim3(512), 256, 0, stream>>>(Yqk, meanv, Av, betaq, betak, energy_int);
  gate_kernel<<<dim3(64), 256, 0, stream>>>(energy_int, Wg, bg, gate, flags, D);

  // ---- gate-guarded: spikes, deferred converts, v branch ----
  spike_qk_write<<<dim3(2048), 256, 0, stream>>>(
      Yqk, meanv, Av, betaq, betak, qb2, kb2, flags);
  prep2_kernel<<<dim3(1024), 256, 0, stream>>>(Wv, Wp, Whv, Wpcat, flags);
  gemm4_bf16_bt<2, 8><<<dim3(8, 32, 1), 256, 0, stream>>>(
      Xh, Whv, bv, bv, Yv, psum_v, psq_v, flags, 1024, 1024);
  bn_finalize_v<<<dim3(4), 256, 0, stream>>>(psum_v, psq_v, gv, meanvv, Avv, flags, 1.0 / M);
  spike_v<<<dim3(2048), 256, 0, stream>>>(Yv, meanvv, Avv, betav, vb2, flags, D);

  // ---- gated attention + spike -> xat2 ([s|s] bf16) ----
  attn_kernel<<<dim3(64, Ntok / 32), 256, 0, stream>>>(
      qb2, kb2, vb2, gate, flags, xat2, Ntok, D, scale);

  // ---- p branch: A=[s|s], B=[Wp_hi|Wp_lo], K=2048; skipped batches analytic ----
  gemm4_bf16_bt<1, 8><<<dim3(8, 32, 1), 256, 0, stream>>>(
      xat2, Wpcat, bp, bp, Yp, psum_qk, psq_qk, flags, 1024, 2048);
  bn_finalize_p<<<dim3(4), 256, 0, stream>>>(psum_qk, psq_qk, gp, bp, meanp, Avp, flags, 1.0 / M);
  bn_spike_f32<<<dim3(2048), 256, 0, stream>>>(Yp, meanp, Avp, betap, bp, flags, out, D);
}

// Round 10
// 84.878 us; speedup vs baseline: 1.0041x; 1.0041x over previous
//
#include <hip/hip_runtime.h>
#include <cstddef>
#include <cstdint>

#define EPS 1e-5f

typedef __bf16 bf16x8 __attribute__((ext_vector_type(8)));
typedef float f32x4 __attribute__((ext_vector_type(4)));
typedef unsigned short u16x8 __attribute__((ext_vector_type(8)));

__device__ __forceinline__ unsigned short f2bf(float f) {
  unsigned u = __builtin_bit_cast(unsigned, f);
  unsigned r = u + 0x7FFFu + ((u >> 16) & 1u);
  return (unsigned short)(r >> 16);
}
__device__ __forceinline__ float bf2f(unsigned short h) {
  unsigned u = (unsigned)h << 16;
  return __builtin_bit_cast(float, u);
}

__device__ __forceinline__ void gl_lds16(const void* g, void* l) {
  __builtin_amdgcn_global_load_lds(
      (const __attribute__((address_space(1))) unsigned int*)g,
      (__attribute__((address_space(3))) unsigned int*)l, 16, 0, 0);
}

// =============== bf16 MFMA GEMM (r7 structure): 4 waves, 128x128, BK=64, dbuf + counted vmcnt ===============
// MODE 0: plain (z via grid.z selects W0/W1)
// MODE 1: p-branch, per-batch EARLY RETURN (no Y write, no stats for skipped batches)
// MODE 2: v-branch, whole-kernel skip when flags[0]==0
template <int MODE>
__global__ __launch_bounds__(256) void gemm_bf16_bt(
    const unsigned short* __restrict__ A,
    const unsigned short* __restrict__ W0, const unsigned short* __restrict__ W1,
    const float* __restrict__ b0, const float* __restrict__ b1,
    unsigned short* __restrict__ Y, double* __restrict__ psum, double* __restrict__ psq,
    const int* __restrict__ flags, int N, int Kc)
{
  if (MODE == 2) { if (flags[0] == 0) return; }

  __shared__ unsigned short As[2][8192];   // 2 x 16 KB
  __shared__ unsigned short Bs[2][8192];   // 2 x 16 KB
  const int tid = threadIdx.x;

  // XCD-chunked swizzle (chunk working set: 2 MB A + 2 MB B -> fits 4 MB per-XCD L2)
  const int bid = blockIdx.x + (blockIdx.y << 3) + (blockIdx.z << 8);
  const int nwg = (int)gridDim.z << 8;
  const int cpx = nwg >> 3;
  const int sw = (bid & 7) * cpx + (bid >> 3);
  const int bx = sw & 7, by = (sw >> 3) & 31, z = sw >> 8;

  if (MODE == 1) { if (flags[1 + (by >> 3)] == 0) return; }

  const unsigned short* Bm = z ? W1 : W0;
  const float* bias = z ? b1 : b0;
  unsigned short* Yz = Y + (size_t)z * 4096 * N;

  const int bm = by * 128, bn = bx * 128;
  const int lane = tid & 63, w = tid >> 6;
  const int wr = w >> 1, wc = w & 1;            // 2x2 waves, 64x64 per wave
  const int l15 = lane & 15, g = lane >> 4;

  f32x4 acc[4][4] = {};

  const unsigned short* aSrc[4]; const unsigned short* bSrc[4]; int dOff[4];
#pragma unroll
  for (int c = 0; c < 4; ++c) {
    int S = c * 256 + tid;
    int row = S >> 3, sp = S & 7;
    int sl = sp ^ (row & 7);
    aSrc[c] = A  + (size_t)(bm + row) * Kc + sl * 8;
    bSrc[c] = Bm + (size_t)(bn + row) * Kc + sl * 8;
    dOff[c] = S * 8;
  }
  int aOff[4][2], bOff[4][2];
#pragma unroll
  for (int i = 0; i < 4; ++i)
#pragma unroll
    for (int t = 0; t < 2; ++t) {
      int rowA = wr * 64 + i * 16 + l15;
      aOff[i][t] = rowA * 64 + ((t * 4 + g) ^ (rowA & 7)) * 8;
      int rowB = wc * 64 + i * 16 + l15;
      bOff[i][t] = rowB * 64 + ((t * 4 + g) ^ (rowB & 7)) * 8;
    }

  const int nk = Kc >> 6;
  // prologue: stage tile 0 (8 gl_lds per thread)
#pragma unroll
  for (int c = 0; c < 4; ++c) { gl_lds16(aSrc[c], &As[0][dOff[c]]); aSrc[c] += 64; }
#pragma unroll
  for (int c = 0; c < 4; ++c) { gl_lds16(bSrc[c], &Bs[0][dOff[c]]); bSrc[c] += 64; }

  int cur = 0;
  for (int kt = 0; kt < nk; ++kt) {
    if (kt + 1 < nk) {
#pragma unroll
      for (int c = 0; c < 4; ++c) { gl_lds16(aSrc[c], &As[cur ^ 1][dOff[c]]); aSrc[c] += 64; }
#pragma unroll
      for (int c = 0; c < 4; ++c) { gl_lds16(bSrc[c], &Bs[cur ^ 1][dOff[c]]); bSrc[c] += 64; }
      asm volatile("s_waitcnt vmcnt(8)" ::: "memory");   // tile kt landed; next stays in flight
    } else {
      asm volatile("s_waitcnt vmcnt(0)" ::: "memory");
    }
    __builtin_amdgcn_s_barrier();
    __builtin_amdgcn_sched_barrier(0);
    {
      const unsigned short* Ac = &As[cur][0];
      const unsigned short* Bc = &Bs[cur][0];
#pragma unroll
      for (int t = 0; t < 2; ++t) {
        bf16x8 af[4], bfr[4];
#pragma unroll
        for (int i = 0; i < 4; ++i) af[i] = *(const bf16x8*)&Ac[aOff[i][t]];
#pragma unroll
        for (int j = 0; j < 4; ++j) bfr[j] = *(const bf16x8*)&Bc[bOff[j][t]];
#pragma unroll
        for (int i = 0; i < 4; ++i)
#pragma unroll
          for (int j = 0; j < 4; ++j)
            acc[i][j] = __builtin_amdgcn_mfma_f32_16x16x32_bf16(af[i], bfr[j], acc[i][j], 0, 0, 0);
      }
    }
    __builtin_amdgcn_s_barrier();
    cur ^= 1;
  }

  // ---- epilogue: bf16 store + per-column partials (of stored values) ----
  const int r0 = bm + wr * 64 + g * 4;
  float csum[4], csq[4];
#pragma unroll
  for (int j = 0; j < 4; ++j) { csum[j] = 0.f; csq[j] = 0.f; }
#pragma unroll
  for (int j = 0; j < 4; ++j) {
    int col = bn + wc * 64 + j * 16 + l15;
    float bv = bias[col];
#pragma unroll
    for (int i = 0; i < 4; ++i)
#pragma unroll
      for (int r = 0; r < 4; ++r) {
        float yv = acc[i][j][r] + bv;
        unsigned short h = f2bf(yv);
        float yb = bf2f(h);
        Yz[(size_t)(r0 + i * 16 + r) * N + col] = h;
        csum[j] += yb;
        csq[j] += yb * yb;
      }
  }
  __syncthreads();
  float* Ls = (float*)&As[0][0];                 // 8 slots x 128 cols, sums then sqs
  const int slot = wr * 4 + g;
#pragma unroll
  for (int j = 0; j < 4; ++j) {
    int ci = wc * 64 + j * 16 + l15;
    Ls[slot * 128 + ci] = csum[j];
    Ls[1024 + slot * 128 + ci] = csq[j];
  }
  __syncthreads();
  if (tid < 128) {
    double s = 0.0, q = 0.0;
#pragma unroll
    for (int sl = 0; sl < 8; ++sl) {
      s += (double)Ls[sl * 128 + tid];
      q += (double)Ls[1024 + sl * 128 + tid];
    }
    size_t o = ((size_t)z * 32 + by) * N + bn + tid;
    psum[o] = s;
    psq[o] = q;
  }
}

// =============== prep1: x, Wq, Wk converts (always needed) ===============
__global__ void prep1_kernel(const float* __restrict__ x,
                             const float* __restrict__ Wq, const float* __restrict__ Wk,
                             unsigned short* __restrict__ Xh, unsigned short* __restrict__ Wh3)
{
  int bid = blockIdx.x, tid = threadIdx.x;
  const float* src; unsigned short* dst; size_t base;
  if (bid < 2048) {
    src = x; dst = Xh; base = ((size_t)bid * 256 + tid) * 8;
  } else if (bid < 2560) {
    src = Wq; dst = Wh3; base = ((size_t)(bid - 2048) * 256 + tid) * 8;
  } else {
    src = Wk; dst = Wh3 + (size_t)1024 * 1024; base = ((size_t)(bid - 2560) * 256 + tid) * 8;
  }
  float4 a = *reinterpret_cast<const float4*>(&src[base]);
  float4 b = *reinterpret_cast<const float4*>(&src[base + 4]);
  u16x8 o;
  o[0] = f2bf(a.x); o[1] = f2bf(a.y); o[2] = f2bf(a.z); o[3] = f2bf(a.w);
  o[4] = f2bf(b.x); o[5] = f2bf(b.y); o[6] = f2bf(b.z); o[7] = f2bf(b.w);
  *reinterpret_cast<u16x8*>(&dst[base]) = o;
}

// =============== prep2: Wv convert + Wp [hi|lo] split (gate-guarded) ===============
__global__ void prep2_kernel(const float* __restrict__ Wv, const float* __restrict__ Wp,
                             unsigned short* __restrict__ Whv, unsigned short* __restrict__ Wpcat,
                             const int* __restrict__ flags)
{
  if (flags[0] == 0) return;
  int bid = blockIdx.x, tid = threadIdx.x;
  if (bid < 512) {
    size_t base = ((size_t)bid * 256 + tid) * 8;
    float4 a = *reinterpret_cast<const float4*>(&Wv[base]);
    float4 b = *reinterpret_cast<const float4*>(&Wv[base + 4]);
    u16x8 o;
    o[0] = f2bf(a.x); o[1] = f2bf(a.y); o[2] = f2bf(a.z); o[3] = f2bf(a.w);
    o[4] = f2bf(b.x); o[5] = f2bf(b.y); o[6] = f2bf(b.z); o[7] = f2bf(b.w);
    *reinterpret_cast<u16x8*>(&Whv[base]) = o;
  } else {
    size_t base = ((size_t)(bid - 512) * 256 + tid) * 8;
    int r = (int)(base >> 10), c = (int)(base & 1023);
    float4 a = *reinterpret_cast<const float4*>(&Wp[base]);
    float4 b = *reinterpret_cast<const float4*>(&Wp[base + 4]);
    u16x8 hi, lo;
    hi[0] = f2bf(a.x); lo[0] = f2bf(a.x - bf2f(hi[0]));
    hi[1] = f2bf(a.y); lo[1] = f2bf(a.y - bf2f(hi[1]));
    hi[2] = f2bf(a.z); lo[2] = f2bf(a.z - bf2f(hi[2]));
    hi[3] = f2bf(a.w); lo[3] = f2bf(a.w - bf2f(hi[3]));
    hi[4] = f2bf(b.x); lo[4] = f2bf(b.x - bf2f(hi[4]));
    hi[5] = f2bf(b.y); lo[5] = f2bf(b.y - bf2f(hi[5]));
    hi[6] = f2bf(b.z); lo[6] = f2bf(b.z - bf2f(hi[6]));
    hi[7] = f2bf(b.w); lo[7] = f2bf(b.w - bf2f(hi[7]));
    unsigned short* Or = Wpcat + (size_t)r * 2048;
    *reinterpret_cast<u16x8*>(&Or[c]) = hi;
    *reinterpret_cast<u16x8*>(&Or[1024 + c]) = lo;
  }
}

// =============== BN finalize (q/k via grid.y, v via runflag); zeroes flags+energy ===============
__global__ void bn_finalize(const double* __restrict__ psum, const double* __restrict__ psq,
                            const float* __restrict__ g0, const float* __restrict__ g1,
                            float* __restrict__ meanv, float* __restrict__ Av,
                            const int* __restrict__ runflag,
                            int* __restrict__ zflags, int* __restrict__ zenergy,
                            int N, double invM)
{
  if (zflags && blockIdx.x == 0 && blockIdx.y == 0) {
    int t = threadIdx.x;
    if (t < 5) zflags[t] = 0;
    if (t >= 64 && t < 128) zenergy[t - 64] = 0;
  }
  if (runflag && runflag[0] == 0) return;
  int z = blockIdx.y;
  const float* g = z ? g1 : g0;
  int c = blockIdx.x * blockDim.x + threadIdx.x;
  const double* ps = psum + (size_t)z * 32 * N + c;
  const double* pq = psq  + (size_t)z * 32 * N + c;
  double s0 = 0, s1 = 0, q0 = 0, q1 = 0;
#pragma unroll
  for (int rb = 0; rb < 32; rb += 2) {
    s0 += ps[(size_t)rb * N];       q0 += pq[(size_t)rb * N];
    s1 += ps[(size_t)(rb + 1) * N]; q1 += pq[(size_t)(rb + 1) * N];
  }
  double s = s0 + s1, q = q0 + q1;
  double m = s * invM;
  double var = q * invM - m * m;
  if (var < 0.0) var = 0.0;
  meanv[(size_t)z * N + c] = (float)m;
  Av[(size_t)z * N + c] = g[(size_t)c] * rsqrtf((float)var + EPS);
}

// =============== BN finalize p: analytic contribution for gated-off batches ===============
__global__ void bn_finalize_p(const double* __restrict__ psum, const double* __restrict__ psq,
                              const float* __restrict__ gp, const float* __restrict__ bp,
                              float* __restrict__ meanv, float* __restrict__ Av,
                              const int* __restrict__ flags, int N, double invM)
{
  int c = blockIdx.x * blockDim.x + threadIdx.x;
  float ybb = bf2f(f2bf(bp[c]));
  double yd = (double)ybb;
  double s = 0.0, q = 0.0;
  for (int rb = 0; rb < 32; ++rb) {
    if (flags[1 + (rb >> 3)]) {
      s += psum[(size_t)rb * N + c];
      q += psq [(size_t)rb * N + c];
    } else {
      s += 128.0 * yd;
      q += 128.0 * yd * yd;
    }
  }
  double m = s * invM;
  double var = q * invM - m * m;
  if (var < 0.0) var = 0.0;
  meanv[c] = (float)m;
  Av[c] = gp[(size_t)c] * rsqrtf((float)var + EPS);
}

// =============== energy count only (read-only; runs before gate) ===============
__global__ void energy_cnt(const unsigned short* __restrict__ Yq,
                           const unsigned short* __restrict__ Yk,
                           const float* __restrict__ meanv, const float* __restrict__ Av,
                           const float* __restrict__ beq, const float* __restrict__ bek,
                           int* __restrict__ energy_int, int N)
{
  const int tid = threadIdx.x;
  const int c0 = (tid * 8) & (N - 1);
  const int head = c0 >> 6;
  const int batch = blockIdx.x >> 7;
  const float* mq = meanv;     const float* aq = Av;
  const float* mk = meanv + N; const float* ak = Av + N;
  __shared__ int bins[16];
  if (tid < 16) bins[tid] = 0;
  __syncthreads();
  int cnt = 0;
#pragma unroll
  for (int j = 0; j < 4; ++j) {
    size_t base = (size_t)blockIdx.x * 8192 + j * 2048 + tid * 8;
    u16x8 yq = *reinterpret_cast<const u16x8*>(&Yq[base]);
    u16x8 yk = *reinterpret_cast<const u16x8*>(&Yk[base]);
#pragma unroll
    for (int e = 0; e < 8; ++e) {
      bool sq = (bf2f(yq[e]) - mq[c0 + e]) * aq[c0 + e] + beq[c0 + e] >= 2.0f;
      bool sk = (bf2f(yk[e]) - mk[c0 + e]) * ak[c0 + e] + bek[c0 + e] >= 2.0f;
      cnt += (sq && sk) ? 1 : 0;
    }
  }
  atomicAdd(&bins[head], cnt);
  __syncthreads();
  if (tid < 16) atomicAdd(&energy_int[batch * 16 + tid], bins[tid]);
}

// =============== q/k spike write (gate-guarded) ===============
__global__ void spike_qk_write(const unsigned short* __restrict__ Yq,
                               const unsigned short* __restrict__ Yk,
                               const float* __restrict__ meanv, const float* __restrict__ Av,
                               const float* __restrict__ beq, const float* __restrict__ bek,
                               unsigned short* __restrict__ qb, unsigned short* __restrict__ kb,
                               const int* __restrict__ flags, int N)
{
  if (flags[0] == 0) return;
  size_t base = ((size_t)blockIdx.x * 256 + threadIdx.x) * 8;
  int c0 = (int)(base & (size_t)(N - 1));
  const float* mq = meanv;     const float* aq = Av;
  const float* mk = meanv + N; const float* ak = Av + N;
  u16x8 yq = *reinterpret_cast<const u16x8*>(&Yq[base]);
  u16x8 yk = *reinterpret_cast<const u16x8*>(&Yk[base]);
  u16x8 oq, ok;
#pragma unroll
  for (int e = 0; e < 8; ++e) {
    oq[e] = ((bf2f(yq[e]) - mq[c0 + e]) * aq[c0 + e] + beq[c0 + e] >= 2.0f) ? 0x3F80 : 0;
    ok[e] = ((bf2f(yk[e]) - mk[c0 + e]) * ak[c0 + e] + bek[c0 + e] >= 2.0f) ? 0x3F80 : 0;
  }
  *reinterpret_cast<u16x8*>(&qb[base]) = oq;
  *reinterpret_cast<u16x8*>(&kb[base]) = ok;
}

// =============== v spike (flag-guarded) ===============
__global__ void spike_v(const unsigned short* __restrict__ Yv,
                        const float* __restrict__ meanv, const float* __restrict__ Av,
                        const float* __restrict__ beta, unsigned short* __restrict__ vb,
                        const int* __restrict__ flags, int N)
{
  if (flags[0] == 0) return;
  size_t base = ((size_t)blockIdx.x * 256 + threadIdx.x) * 8;
  int c0 = (int)(base & (size_t)(N - 1));
  u16x8 y8 = *reinterpret_cast<const u16x8*>(&Yv[base]);
  u16x8 o;
#pragma unroll
  for (int e = 0; e < 8; ++e)
    o[e] = ((bf2f(y8[e]) - meanv[c0 + e]) * Av[c0 + e] + beta[c0 + e] >= 2.0f) ? 0x3F80 : 0;
  *reinterpret_cast<u16x8*>(&vb[base]) = o;
}

// =============== final output spike (flag-aware: skipped batches use y = bf16(bp)) ===============
__global__ void bn_spike_f32(const unsigned short* __restrict__ Y,
                             const float* __restrict__ meanv, const float* __restrict__ Av,
                             const float* __restrict__ beta, const float* __restrict__ bp,
                             const int* __restrict__ flags, float* __restrict__ S, int N)
{
  size_t base = ((size_t)blockIdx.x * 256 + threadIdx.x) * 8;
  int c0 = (int)(base & (size_t)(N - 1));
  int batch = (int)(base >> 20);
  float y[8];
  if (flags[1 + batch]) {
    u16x8 y8 = *reinterpret_cast<const u16x8*>(&Y[base]);
#pragma unroll
    for (int e = 0; e < 8; ++e) y[e] = bf2f(y8[e]);
  } else {
#pragma unroll
    for (int e = 0; e < 8; ++e) y[e] = bf2f(f2bf(bp[c0 + e]));
  }
  float4 o0, o1;
  o0.x = ((y[0] - meanv[c0 + 0]) * Av[c0 + 0] + beta[c0 + 0] >= 2.0f) ? 1.f : 0.f;
  o0.y = ((y[1] - meanv[c0 + 1]) * Av[c0 + 1] + beta[c0 + 1] >= 2.0f) ? 1.f : 0.f;
  o0.z = ((y[2] - meanv[c0 + 2]) * Av[c0 + 2] + beta[c0 + 2] >= 2.0f) ? 1.f : 0.f;
  o0.w = ((y[3] - meanv[c0 + 3]) * Av[c0 + 3] + beta[c0 + 3] >= 2.0f) ? 1.f : 0.f;
  o1.x = ((y[4] - meanv[c0 + 4]) * Av[c0 + 4] + beta[c0 + 4] >= 2.0f) ? 1.f : 0.f;
  o1.y = ((y[5] - meanv[c0 + 5]) * Av[c0 + 5] + beta[c0 + 5] >= 2.0f) ? 1.f : 0.f;
  o1.z = ((y[6] - meanv[c0 + 6]) * Av[c0 + 6] + beta[c0 + 6] >= 2.0f) ? 1.f : 0.f;
  o1.w = ((y[7] - meanv[c0 + 7]) * Av[c0 + 7] + beta[c0 + 7] >= 2.0f) ? 1.f : 0.f;
  *reinterpret_cast<float4*>(&S[base]) = o0;
  *reinterpret_cast<float4*>(&S[base + 4]) = o1;
}

// =============== gate ===============
__global__ void gate_kernel(const int* __restrict__ energy_int, const float* __restrict__ Wg,
                            const float* __restrict__ bg, float* __restrict__ gate,
                            int* __restrict__ flags, int D)
{
  int b = blockIdx.x >> 4, hp = blockIdx.x & 15;
  int tid = threadIdx.x;
  float e[16];
#pragma unroll
  for (int h = 0; h < 16; ++h) e[h] = (float)energy_int[b * 16 + h] * (1.f / 1024.f);
  float s = 0.f;
  for (int j = tid; j < D; j += 256) s = fmaf(e[j & 15], Wg[(size_t)hp * D + j], s);
  __shared__ float red[256];
  red[tid] = s;
  __syncthreads();
  for (int off = 128; off; off >>= 1) {
    if (tid < off) red[tid] += red[tid + off];
    __syncthreads();
  }
  if (tid == 0) {
    int gv = (red[0] + bg[hp] >= 0.5f) ? 1 : 0;
    gate[blockIdx.x] = (float)gv;
    if (gv) { atomicOr(&flags[0], 1); atomicOr(&flags[1 + b], 1); }
  }
}

// =============== gated attention + spike -> xat2 bf16 [4096][2048]=[s|s] ===============
__global__ __launch_bounds__(256) void attn_kernel(
    const unsigned short* __restrict__ qb, const unsigned short* __restrict__ kb,
    const unsigned short* __restrict__ vb, const float* __restrict__ gate,
    const int* __restrict__ flags, unsigned short* __restrict__ xs,
    int Ntok, int D, float scale)
{
  int bh = blockIdx.x;
  int b = bh >> 4, h = bh & 15;
  if (flags[1 + b] == 0) return;
  int n0 = blockIdx.y * 32;
  int tid = threadIdx.x;
  unsigned short* outbase = xs + (size_t)(b * Ntok + n0) * 2048 + h * 64;

  if (gate[bh] == 0.f) {
    ushort4 zv = {0, 0, 0, 0};
    for (int i = tid; i < 32 * 16; i += 256) {
      int r = i >> 4, c4 = (i & 15) << 2;
      *reinterpret_cast<ushort4*>(&outbase[(size_t)r * 2048 + c4]) = zv;
      *reinterpret_cast<ushort4*>(&outbase[(size_t)r * 2048 + 1024 + c4]) = zv;
    }
    return;
  }

  __shared__ float qs[32][68], ks[32][68], vs[32][68], Ss[32][36];
  const unsigned short* qg = qb + (size_t)b * Ntok * D + h * 64;
  const unsigned short* kg = kb + (size_t)b * Ntok * D + h * 64;
  const unsigned short* vg = vb + (size_t)b * Ntok * D + h * 64;

  {
    int r = tid >> 3, c8 = (tid & 7) * 8;
    u16x8 t = *reinterpret_cast<const u16x8*>(&qg[(size_t)(n0 + r) * D + c8]);
#pragma unroll
    for (int e = 0; e < 8; ++e) qs[r][c8 + e] = bf2f(t[e]);
  }

  float acc[8];
#pragma unroll
  for (int j = 0; j < 8; ++j) acc[j] = 0.f;
  const int nloc = tid >> 3;
  const int dd0 = (tid & 7) * 8;

  for (int mt = 0; mt < Ntok / 32; ++mt) {
    int m0 = mt * 32;
    __syncthreads();
    {
      int r = tid >> 3, c8 = (tid & 7) * 8;
      u16x8 tk = *reinterpret_cast<const u16x8*>(&kg[(size_t)(m0 + r) * D + c8]);
      u16x8 tv = *reinterpret_cast<const u16x8*>(&vg[(size_t)(m0 + r) * D + c8]);
#pragma unroll
      for (int e = 0; e < 8; ++e) { ks[r][c8 + e] = bf2f(tk[e]); vs[r][c8 + e] = bf2f(tv[e]); }
    }
    __syncthreads();
    {
      int np = tid >> 3;
      int mp0 = (tid & 7) * 4;
      float s0 = 0.f, s1 = 0.f, s2 = 0.f, s3 = 0.f;
#pragma unroll 8
      for (int d = 0; d < 64; ++d) {
        float qv = qs[np][d];
        s0 = fmaf(qv, ks[mp0 + 0][d], s0);
        s1 = fmaf(qv, ks[mp0 + 1][d], s1);
        s2 = fmaf(qv, ks[mp0 + 2][d], s2);
        s3 = fmaf(qv, ks[mp0 + 3][d], s3);
      }
      Ss[np][mp0 + 0] = s0; Ss[np][mp0 + 1] = s1;
      Ss[np][mp0 + 2] = s2; Ss[np][mp0 + 3] = s3;
    }
    __syncthreads();
#pragma unroll 8
    for (int mp = 0; mp < 32; ++mp) {
      float sv = Ss[nloc][mp];
#pragma unroll
      for (int j = 0; j < 8; ++j) acc[j] = fmaf(sv, vs[mp][dd0 + j], acc[j]);
    }
  }

#pragma unroll
  for (int j = 0; j < 8; ++j) {
    float x = scale * acc[j];
    unsigned short sp = (x >= 1.0f) ? 0x3F80 : 0;
    outbase[(size_t)nloc * 2048 + dd0 + j] = sp;
    outbase[(size_t)nloc * 2048 + 1024 + dd0 + j] = sp;
  }
}

// ======================================================================
extern "C" void kernel_launch(void* const* d_in, const int* in_sizes, int n_in,
                              void* d_out, int out_size, void* d_ws, size_t ws_size,
                              hipStream_t stream)
{
  (void)in_sizes; (void)n_in; (void)out_size; (void)ws_size;
  const int Ntok = 1024, D = 1024;
  const int M = 4096;
  const float scale = 0.5946035575013605f;      // 64^(-1/8)

  const float* x     = (const float*)d_in[0];
  const float* Wq    = (const float*)d_in[1];
  const float* bq    = (const float*)d_in[2];
  const float* gq    = (const float*)d_in[3];
  const float* betaq = (const float*)d_in[4];
  const float* Wk    = (const float*)d_in[5];
  const float* bk    = (const float*)d_in[6];
  const float* gk    = (const float*)d_in[7];
  const float* betak = (const float*)d_in[8];
  const float* Wv    = (const float*)d_in[9];
  const float* bv    = (const float*)d_in[10];
  const float* gv    = (const float*)d_in[11];
  const float* betav = (const float*)d_in[12];
  const float* Wp    = (const float*)d_in[13];
  const float* bp    = (const float*)d_in[14];
  const float* gp    = (const float*)d_in[15];
  const float* betap = (const float*)d_in[16];
  const float* Wg    = (const float*)d_in[17];
  const float* bg    = (const float*)d_in[18];

  char* w = (char*)d_ws;
  const size_t MB = 1024 * 1024;
  const size_t MN = (size_t)M * D;
  unsigned short* Y3bf  = (unsigned short*)(w + 0 * MB);    // q,k,v pre-activations (24 MB)
  unsigned short* xat2  = (unsigned short*)(w + 0 * MB);    // alias 16 MB (q,k slots dead)
  unsigned short* Yv    = Y3bf + 2 * MN;                    // v slot (survives alias)
  unsigned short* Yp    = (unsigned short*)(w + 24 * MB);   // 8 MB
  unsigned short* Wpcat = (unsigned short*)(w + 32 * MB);   // 4 MB
  unsigned short* Xh    = (unsigned short*)(w + 48 * MB);   // 8 MB
  unsigned short* Wh3   = (unsigned short*)(w + 56 * MB);   // 6 MB
  unsigned short* qb2   = (unsigned short*)(w + 62 * MB);   // 8 MB
  unsigned short* kb2   = (unsigned short*)(w + 70 * MB);   // 8 MB
  unsigned short* vb2   = (unsigned short*)(w + 78 * MB);   // 8 MB
  double* psum   = (double*)(w + 86 * MB);                  // 768 KB
  double* psq    = (double*)(w + 87 * MB);                  // 768 KB
  float*  meanv  = (float*)(w + 88 * MB);                   // 4 z-slots x 1024
  float*  Av     = (float*)(w + 88 * MB + 16384);
  int*    energy_int = (int*)(w + 88 * MB + 32768);
  int*    flags  = (int*)(w + 88 * MB + 32768 + 512);       // [any, batch0..3]
  float*  gate   = (float*)(w + 88 * MB + 32768 + 1024);

  float* out = (float*)d_out;
  unsigned short* Whq = Wh3;
  unsigned short* Whk = Wh3 + MN / 4;
  unsigned short* Whv = Wh3 + MN / 2;
  float* meanp = meanv + 3 * D;
  float* Avp   = Av + 3 * D;

  // ---- converts (always-needed) ----
  prep1_kernel<<<dim3(3072), 256, 0, stream>>>(x, Wq, Wk, Xh, Wh3);

  // ---- q,k GEMM (+fused stats), r7 structure ----
  gemm_bf16_bt<0><<<dim3(8, 32, 2), 256, 0, stream>>>(
      Xh, Whq, Whk, bq, bk, Y3bf, psum, psq, nullptr, D, 1024);
  bn_finalize<<<dim3(4, 2), 256, 0, stream>>>(
      psum, psq, gq, gk, meanv, Av, nullptr, flags, energy_int, D, 1.0 / M);

  // ---- energy (count-only) + gate ----
  energy_cnt<<<dim3(512), 256, 0, stream>>>(
      Y3bf, Y3bf + MN, meanv, Av, betaq, betak, energy_int, D);
  gate_kernel<<<dim3(64), 256, 0, stream>>>(energy_int, Wg, bg, gate, flags, D);

  // ---- gate-guarded: spikes, deferred converts, v branch ----
  spike_qk_write<<<dim3(2048), 256, 0, stream>>>(
      Y3bf, Y3bf + MN, meanv, Av, betaq, betak, qb2, kb2, flags, D);
  prep2_kernel<<<dim3(1024), 256, 0, stream>>>(Wv, Wp, Whv, Wpcat, flags);
  gemm_bf16_bt<2><<<dim3(8, 32, 1), 256, 0, stream>>>(
      Xh, Whv, Whv, bv, bv, Yv, psum + 2 * 32 * (size_t)D, psq + 2 * 32 * (size_t)D,
      flags, D, 1024);
  bn_finalize<<<dim3(4, 1), 256, 0, stream>>>(
      psum + 2 * 32 * (size_t)D, psq + 2 * 32 * (size_t)D, gv, gv,
      meanv + 2 * D, Av + 2 * D, flags, nullptr, nullptr, D, 1.0 / M);
  spike_v<<<dim3(2048), 256, 0, stream>>>(Yv, meanv + 2 * D, Av + 2 * D, betav, vb2, flags, D);

  // ---- gated attention + spike -> xat2 ([s|s] bf16) ----
  attn_kernel<<<dim3(64, Ntok / 32), 256, 0, stream>>>(
      qb2, kb2, vb2, gate, flags, xat2, Ntok, D, scale);

  // ---- p branch: A=[s|s], B=[Wp_hi|Wp_lo], K=2048; skipped batches early-return ----
  gemm_bf16_bt<1><<<dim3(8, 32, 1), 256, 0, stream>>>(
      xat2, Wpcat, Wpcat, bp, bp, Yp, psum, psq, flags, D, 2048);
  bn_finalize_p<<<dim3(4), 256, 0, stream>>>(psum, psq, gp, bp, meanp, Avp, flags, D, 1.0 / M);
  bn_spike_f32<<<dim3(2048), 256, 0, stream>>>(Yp, meanp, Avp, betap, bp, flags, out, D);
}

// Round 11
// 75.983 us; speedup vs baseline: 1.1216x; 1.1171x over previous
//
#include <hip/hip_runtime.h>
#include <cstddef>
#include <cstdint>

#define EPS 1e-5f

typedef __bf16 bf16x8 __attribute__((ext_vector_type(8)));
typedef float f32x4 __attribute__((ext_vector_type(4)));
typedef unsigned short u16x8 __attribute__((ext_vector_type(8)));

__device__ __forceinline__ unsigned short f2bf(float f) {
  unsigned u = __builtin_bit_cast(unsigned, f);
  unsigned r = u + 0x7FFFu + ((u >> 16) & 1u);
  return (unsigned short)(r >> 16);
}
__device__ __forceinline__ float bf2f(unsigned short h) {
  unsigned u = (unsigned)h << 16;
  return __builtin_bit_cast(float, u);
}

__device__ __forceinline__ void gl_lds16(const void* g, void* l) {
  __builtin_amdgcn_global_load_lds(
      (const __attribute__((address_space(1))) unsigned int*)g,
      (__attribute__((address_space(3))) unsigned int*)l, 16, 0, 0);
}

// =============== bf16 MFMA GEMM: dbuf + COUNTED vmcnt (prefetch never drained) ===============
// MODE 0: plain (z selects W0/W1 via grid.z)
// MODE 1: per-batch skip of K-loop (p-branch; epilogue still writes bias + stats)
// MODE 2: full kernel skip when flags[0]==0 (v-branch; outputs unread in that case)
template <int MODE>
__global__ __launch_bounds__(256) void gemm_bf16_bt(
    const unsigned short* __restrict__ A,
    const unsigned short* __restrict__ W0, const unsigned short* __restrict__ W1,
    const float* __restrict__ b0, const float* __restrict__ b1,
    unsigned short* __restrict__ Y, double* __restrict__ psum, double* __restrict__ psq,
    const int* __restrict__ flags, int N, int Kc)
{
  if (MODE == 2) { if (flags[0] == 0) return; }

  __shared__ unsigned short As[2][8192];   // 2 x 16 KB
  __shared__ unsigned short Bs[2][8192];   // 2 x 16 KB
  const int tid = threadIdx.x;

  // XCD-chunked swizzle
  const int bid = blockIdx.x + (blockIdx.y << 3) + (blockIdx.z << 8);
  const int nwg = (int)gridDim.z << 8;
  const int cpx = nwg >> 3;
  const int sw = (bid & 7) * cpx + (bid >> 3);
  const int bx = sw & 7, by = (sw >> 3) & 31, z = sw >> 8;

  const unsigned short* Bm = z ? W1 : W0;
  const float* bias = z ? b1 : b0;
  unsigned short* Yz = Y + (size_t)z * 4096 * N;

  const int bm = by * 128, bn = bx * 128;
  const int lane = tid & 63, w = tid >> 6;
  const int wr = w >> 1, wc = w & 1;            // wave tile 64x64
  const int l15 = lane & 15, g = lane >> 4;

  f32x4 acc[4][4] = {};

  bool skip = false;
  if (MODE == 1) skip = (flags[1 + (by >> 3)] == 0);

  if (!skip) {
    const unsigned short* aSrc[4]; const unsigned short* bSrc[4]; int dOff[4];
#pragma unroll
    for (int c = 0; c < 4; ++c) {
      int S = c * 256 + tid;
      int row = S >> 3, sp = S & 7;
      int sl = sp ^ (row & 7);
      aSrc[c] = A  + (size_t)(bm + row) * Kc + sl * 8;
      bSrc[c] = Bm + (size_t)(bn + row) * Kc + sl * 8;
      dOff[c] = S * 8;
    }
    int aOff[4][2], bOff[4][2];
#pragma unroll
    for (int i = 0; i < 4; ++i)
#pragma unroll
      for (int t = 0; t < 2; ++t) {
        int rowA = wr * 64 + i * 16 + l15;
        aOff[i][t] = rowA * 64 + ((t * 4 + g) ^ (rowA & 7)) * 8;
        int rowB = wc * 64 + i * 16 + l15;
        bOff[i][t] = rowB * 64 + ((t * 4 + g) ^ (rowB & 7)) * 8;
      }

    const int nk = Kc >> 6;
    // prologue: stage tile 0 into buf 0 (8 gl_lds per wave)
#pragma unroll
    for (int c = 0; c < 4; ++c) { gl_lds16(aSrc[c], &As[0][dOff[c]]); aSrc[c] += 64; }
#pragma unroll
    for (int c = 0; c < 4; ++c) { gl_lds16(bSrc[c], &Bs[0][dOff[c]]); bSrc[c] += 64; }

    int cur = 0;
    for (int kt = 0; kt < nk; ++kt) {
      if (kt + 1 < nk) {
        // issue next-tile stage; keep it IN FLIGHT across the barriers
#pragma unroll
        for (int c = 0; c < 4; ++c) { gl_lds16(aSrc[c], &As[cur ^ 1][dOff[c]]); aSrc[c] += 64; }
#pragma unroll
        for (int c = 0; c < 4; ++c) { gl_lds16(bSrc[c], &Bs[cur ^ 1][dOff[c]]); bSrc[c] += 64; }
        asm volatile("s_waitcnt vmcnt(8)" ::: "memory");   // tile kt landed (8 newest allowed out)
      } else {
        asm volatile("s_waitcnt vmcnt(0)" ::: "memory");   // last tile: full drain
      }
      __builtin_amdgcn_s_barrier();
      __builtin_amdgcn_sched_barrier(0);
      {
        const unsigned short* Ac = &As[cur][0];
        const unsigned short* Bc = &Bs[cur][0];
#pragma unroll
        for (int t = 0; t < 2; ++t) {
          bf16x8 af[4], bfr[4];
#pragma unroll
          for (int i = 0; i < 4; ++i) af[i] = *(const bf16x8*)&Ac[aOff[i][t]];
#pragma unroll
          for (int j = 0; j < 4; ++j) bfr[j] = *(const bf16x8*)&Bc[bOff[j][t]];
#pragma unroll
          for (int i = 0; i < 4; ++i)
#pragma unroll
            for (int j = 0; j < 4; ++j)
              acc[i][j] = __builtin_amdgcn_mfma_f32_16x16x32_bf16(af[i], bfr[j], acc[i][j], 0, 0, 0);
        }
      }
      __builtin_amdgcn_s_barrier();   // readers done; buf[cur] safe to overwrite next iter
      cur ^= 1;
    }
  }

  // ---- epilogue: bf16 store + per-column partials (of stored values) ----
  const int r0 = bm + wr * 64 + g * 4;
  float csum[4], csq[4];
#pragma unroll
  for (int j = 0; j < 4; ++j) { csum[j] = 0.f; csq[j] = 0.f; }
#pragma unroll
  for (int j = 0; j < 4; ++j) {
    int col = bn + wc * 64 + j * 16 + l15;
    float bv = bias[col];
#pragma unroll
    for (int i = 0; i < 4; ++i)
#pragma unroll
      for (int r = 0; r < 4; ++r) {
        float yv = acc[i][j][r] + bv;
        unsigned short h = f2bf(yv);
        float yb = bf2f(h);
        Yz[(size_t)(r0 + i * 16 + r) * N + col] = h;
        csum[j] += yb;
        csq[j] += yb * yb;
      }
  }
  __syncthreads();
  float* Ls = (float*)&As[0][0];                 // 8 slots x 128 cols, sums then sqs
  const int slot = wr * 4 + g;
#pragma unroll
  for (int j = 0; j < 4; ++j) {
    int ci = wc * 64 + j * 16 + l15;
    Ls[slot * 128 + ci] = csum[j];
    Ls[1024 + slot * 128 + ci] = csq[j];
  }
  __syncthreads();
  if (tid < 128) {
    double s = 0.0, q = 0.0;
#pragma unroll
    for (int sl = 0; sl < 8; ++sl) {
      s += (double)Ls[sl * 128 + tid];
      q += (double)Ls[1024 + sl * 128 + tid];
    }
    size_t o = ((size_t)z * 32 + by) * N + bn + tid;
    psum[o] = s;
    psq[o] = q;
  }
}

// =============== prep1: x, Wq, Wk converts (always needed) ===============
// blocks 0..2047: x -> Xh ; 2048..2559: Wq ; 2560..3071: Wk
__global__ void prep1_kernel(const float* __restrict__ x,
                             const float* __restrict__ Wq, const float* __restrict__ Wk,
                             unsigned short* __restrict__ Xh, unsigned short* __restrict__ Wh3)
{
  int bid = blockIdx.x, tid = threadIdx.x;
  const float* src; unsigned short* dst; size_t base;
  if (bid < 2048) {
    src = x; dst = Xh; base = ((size_t)bid * 256 + tid) * 8;
  } else if (bid < 2560) {
    src = Wq; dst = Wh3; base = ((size_t)(bid - 2048) * 256 + tid) * 8;
  } else {
    src = Wk; dst = Wh3 + (size_t)1024 * 1024; base = ((size_t)(bid - 2560) * 256 + tid) * 8;
  }
  float4 a = *reinterpret_cast<const float4*>(&src[base]);
  float4 b = *reinterpret_cast<const float4*>(&src[base + 4]);
  u16x8 o;
  o[0] = f2bf(a.x); o[1] = f2bf(a.y); o[2] = f2bf(a.z); o[3] = f2bf(a.w);
  o[4] = f2bf(b.x); o[5] = f2bf(b.y); o[6] = f2bf(b.z); o[7] = f2bf(b.w);
  *reinterpret_cast<u16x8*>(&dst[base]) = o;
}

// =============== prep2: Wv convert + Wp [hi|lo] split — only if some gate fired ===============
// blocks 0..511: Wv -> Whv ; 512..1023: Wp -> Wpcat
__global__ void prep2_kernel(const float* __restrict__ Wv, const float* __restrict__ Wp,
                             unsigned short* __restrict__ Whv, unsigned short* __restrict__ Wpcat,
                             const int* __restrict__ flags)
{
  if (flags[0] == 0) return;
  int bid = blockIdx.x, tid = threadIdx.x;
  if (bid < 512) {
    size_t base = ((size_t)bid * 256 + tid) * 8;
    float4 a = *reinterpret_cast<const float4*>(&Wv[base]);
    float4 b = *reinterpret_cast<const float4*>(&Wv[base + 4]);
    u16x8 o;
    o[0] = f2bf(a.x); o[1] = f2bf(a.y); o[2] = f2bf(a.z); o[3] = f2bf(a.w);
    o[4] = f2bf(b.x); o[5] = f2bf(b.y); o[6] = f2bf(b.z); o[7] = f2bf(b.w);
    *reinterpret_cast<u16x8*>(&Whv[base]) = o;
  } else {
    size_t base = ((size_t)(bid - 512) * 256 + tid) * 8;
    int r = (int)(base >> 10), c = (int)(base & 1023);
    float4 a = *reinterpret_cast<const float4*>(&Wp[base]);
    float4 b = *reinterpret_cast<const float4*>(&Wp[base + 4]);
    u16x8 hi, lo;
    hi[0] = f2bf(a.x); lo[0] = f2bf(a.x - bf2f(hi[0]));
    hi[1] = f2bf(a.y); lo[1] = f2bf(a.y - bf2f(hi[1]));
    hi[2] = f2bf(a.z); lo[2] = f2bf(a.z - bf2f(hi[2]));
    hi[3] = f2bf(a.w); lo[3] = f2bf(a.w - bf2f(hi[3]));
    hi[4] = f2bf(b.x); lo[4] = f2bf(b.x - bf2f(hi[4]));
    hi[5] = f2bf(b.y); lo[5] = f2bf(b.y - bf2f(hi[5]));
    hi[6] = f2bf(b.z); lo[6] = f2bf(b.z - bf2f(hi[6]));
    hi[7] = f2bf(b.w); lo[7] = f2bf(b.w - bf2f(hi[7]));
    unsigned short* Or = Wpcat + (size_t)r * 2048;
    *reinterpret_cast<u16x8*>(&Or[c]) = hi;
    *reinterpret_cast<u16x8*>(&Or[1024 + c]) = lo;
  }
}

// =============== BN finalize (32 partial blocks), fully unrolled ===============
__global__ void bn_finalize(const double* __restrict__ psum, const double* __restrict__ psq,
                            const float* __restrict__ g0, const float* __restrict__ g1,
                            float* __restrict__ meanv, float* __restrict__ Av,
                            const int* __restrict__ runflag,
                            int* __restrict__ zflags, int* __restrict__ zenergy,
                            int N, double invM)
{
  if (zflags && blockIdx.x == 0 && blockIdx.y == 0) {
    int t = threadIdx.x;
    if (t < 5) zflags[t] = 0;
    if (t >= 64 && t < 128) zenergy[t - 64] = 0;
  }
  if (runflag && runflag[0] == 0) return;
  int z = blockIdx.y;
  const float* g = z ? g1 : g0;
  int c = blockIdx.x * blockDim.x + threadIdx.x;
  const double* ps = psum + (size_t)z * 32 * N + c;
  const double* pq = psq  + (size_t)z * 32 * N + c;
  double s0 = 0, s1 = 0, q0 = 0, q1 = 0;
#pragma unroll
  for (int rb = 0; rb < 32; rb += 2) {
    s0 += ps[(size_t)rb * N];       q0 += pq[(size_t)rb * N];
    s1 += ps[(size_t)(rb + 1) * N]; q1 += pq[(size_t)(rb + 1) * N];
  }
  double s = s0 + s1, q = q0 + q1;
  double m = s * invM;
  double var = q * invM - m * m;
  if (var < 0.0) var = 0.0;
  meanv[(size_t)z * N + c] = (float)m;
  Av[(size_t)z * N + c] = g[(size_t)c] * rsqrtf((float)var + EPS);
}

// =============== q/k spike + fused energy popcount (deterministic int atomics) ===============
__global__ void spike_qk_energy(const unsigned short* __restrict__ Yq,
                                const unsigned short* __restrict__ Yk,
                                const float* __restrict__ meanv, const float* __restrict__ Av,
                                const float* __restrict__ beq, const float* __restrict__ bek,
                                unsigned short* __restrict__ qb, unsigned short* __restrict__ kb,
                                int* __restrict__ energy_int, int N)
{
  const int tid = threadIdx.x;
  const int c0 = (tid * 8) & (N - 1);
  const int head = c0 >> 6;
  const int batch = blockIdx.x >> 7;
  const float* mq = meanv;            const float* aq = Av;
  const float* mk = meanv + N;        const float* ak = Av + N;
  __shared__ int bins[16];
  if (tid < 16) bins[tid] = 0;
  __syncthreads();
  int cnt = 0;
#pragma unroll
  for (int j = 0; j < 4; ++j) {
    size_t base = (size_t)blockIdx.x * 8192 + j * 2048 + tid * 8;
    u16x8 yq = *reinterpret_cast<const u16x8*>(&Yq[base]);
    u16x8 yk = *reinterpret_cast<const u16x8*>(&Yk[base]);
    u16x8 oq, ok;
#pragma unroll
    for (int e = 0; e < 8; ++e) {
      bool sq = (bf2f(yq[e]) - mq[c0 + e]) * aq[c0 + e] + beq[c0 + e] >= 2.0f;
      bool sk = (bf2f(yk[e]) - mk[c0 + e]) * ak[c0 + e] + bek[c0 + e] >= 2.0f;
      oq[e] = sq ? 0x3F80 : 0;
      ok[e] = sk ? 0x3F80 : 0;
      cnt += (sq && sk) ? 1 : 0;
    }
    *reinterpret_cast<u16x8*>(&qb[base]) = oq;
    *reinterpret_cast<u16x8*>(&kb[base]) = ok;
  }
  atomicAdd(&bins[head], cnt);
  __syncthreads();
  if (tid < 16) atomicAdd(&energy_int[batch * 16 + tid], bins[tid]);
}

// =============== v spike (flag-guarded) ===============
__global__ void spike_v(const unsigned short* __restrict__ Yv,
                        const float* __restrict__ meanv, const float* __restrict__ Av,
                        const float* __restrict__ beta, unsigned short* __restrict__ vb,
                        const int* __restrict__ flags, int N)
{
  if (flags[0] == 0) return;
  size_t base = ((size_t)blockIdx.x * 256 + threadIdx.x) * 8;
  int c0 = (int)(base & (size_t)(N - 1));
  u16x8 y8 = *reinterpret_cast<const u16x8*>(&Yv[base]);
  u16x8 o;
#pragma unroll
  for (int e = 0; e < 8; ++e)
    o[e] = ((bf2f(y8[e]) - meanv[c0 + e]) * Av[c0 + e] + beta[c0 + e] >= 2.0f) ? 0x3F80 : 0;
  *reinterpret_cast<u16x8*>(&vb[base]) = o;
}

// =============== final output spike ===============
__global__ void bn_spike_f32(const unsigned short* __restrict__ Y,
                             const float* __restrict__ meanv, const float* __restrict__ Av,
                             const float* __restrict__ beta, float* __restrict__ S, int N)
{
  size_t base = ((size_t)blockIdx.x * 256 + threadIdx.x) * 8;
  int c0 = (int)(base & (size_t)(N - 1));
  u16x8 y8 = *reinterpret_cast<const u16x8*>(&Y[base]);
  float4 o0, o1;
  o0.x = ((bf2f(y8[0]) - meanv[c0 + 0]) * Av[c0 + 0] + beta[c0 + 0] >= 2.0f) ? 1.f : 0.f;
  o0.y = ((bf2f(y8[1]) - meanv[c0 + 1]) * Av[c0 + 1] + beta[c0 + 1] >= 2.0f) ? 1.f : 0.f;
  o0.z = ((bf2f(y8[2]) - meanv[c0 + 2]) * Av[c0 + 2] + beta[c0 + 2] >= 2.0f) ? 1.f : 0.f;
  o0.w = ((bf2f(y8[3]) - meanv[c0 + 3]) * Av[c0 + 3] + beta[c0 + 3] >= 2.0f) ? 1.f : 0.f;
  o1.x = ((bf2f(y8[4]) - meanv[c0 + 4]) * Av[c0 + 4] + beta[c0 + 4] >= 2.0f) ? 1.f : 0.f;
  o1.y = ((bf2f(y8[5]) - meanv[c0 + 5]) * Av[c0 + 5] + beta[c0 + 5] >= 2.0f) ? 1.f : 0.f;
  o1.z = ((bf2f(y8[6]) - meanv[c0 + 6]) * Av[c0 + 6] + beta[c0 + 6] >= 2.0f) ? 1.f : 0.f;
  o1.w = ((bf2f(y8[7]) - meanv[c0 + 7]) * Av[c0 + 7] + beta[c0 + 7] >= 2.0f) ? 1.f : 0.f;
  *reinterpret_cast<float4*>(&S[base]) = o0;
  *reinterpret_cast<float4*>(&S[base + 4]) = o1;
}

// =============== gate: energy_int/1024 (exact) -> gate + any-flags ===============
__global__ void gate_kernel(const int* __restrict__ energy_int, const float* __restrict__ Wg,
                            const float* __restrict__ bg, float* __restrict__ gate,
                            int* __restrict__ flags, int D)
{
  int b = blockIdx.x >> 4, hp = blockIdx.x & 15;
  int tid = threadIdx.x;
  float e[16];
#pragma unroll
  for (int h = 0; h < 16; ++h) e[h] = (float)energy_int[b * 16 + h] * (1.f / 1024.f);
  float s = 0.f;
  for (int j = tid; j < D; j += 256) s = fmaf(e[j & 15], Wg[(size_t)hp * D + j], s);
  __shared__ float red[256];
  red[tid] = s;
  __syncthreads();
  for (int off = 128; off; off >>= 1) {
    if (tid < off) red[tid] += red[tid + off];
    __syncthreads();
  }
  if (tid == 0) {
    int gv = (red[0] + bg[hp] >= 0.5f) ? 1 : 0;
    gate[blockIdx.x] = (float)gv;
    if (gv) { atomicOr(&flags[0], 1); atomicOr(&flags[1 + b], 1); }
  }
}

// =============== gated attention + spike -> xat2 bf16 [4096][2048]=[s|s] ===============
__global__ __launch_bounds__(256) void attn_kernel(
    const unsigned short* __restrict__ qb, const unsigned short* __restrict__ kb,
    const unsigned short* __restrict__ vb, const float* __restrict__ gate,
    const int* __restrict__ flags, unsigned short* __restrict__ xs,
    int Ntok, int D, float scale)
{
  int bh = blockIdx.x;
  int b = bh >> 4, h = bh & 15;
  if (flags[1 + b] == 0) return;     // whole batch gated off -> p-GEMM skips it, xs unread
  int n0 = blockIdx.y * 32;
  int tid = threadIdx.x;
  unsigned short* outbase = xs + (size_t)(b * Ntok + n0) * 2048 + h * 64;

  if (gate[bh] == 0.f) {
    ushort4 zv = {0, 0, 0, 0};
    for (int i = tid; i < 32 * 16; i += 256) {
      int r = i >> 4, c4 = (i & 15) << 2;
      *reinterpret_cast<ushort4*>(&outbase[(size_t)r * 2048 + c4]) = zv;
      *reinterpret_cast<ushort4*>(&outbase[(size_t)r * 2048 + 1024 + c4]) = zv;
    }
    return;
  }

  __shared__ float qs[32][68], ks[32][68], vs[32][68], Ss[32][36];
  const unsigned short* qg = qb + (size_t)b * Ntok * D + h * 64;
  const unsigned short* kg = kb + (size_t)b * Ntok * D + h * 64;
  const unsigned short* vg = vb + (size_t)b * Ntok * D + h * 64;

  {
    int r = tid >> 3, c8 = (tid & 7) * 8;
    u16x8 t = *reinterpret_cast<const u16x8*>(&qg[(size_t)(n0 + r) * D + c8]);
#pragma unroll
    for (int e = 0; e < 8; ++e) qs[r][c8 + e] = bf2f(t[e]);
  }

  float acc[8];
#pragma unroll
  for (int j = 0; j < 8; ++j) acc[j] = 0.f;
  const int nloc = tid >> 3;
  const int dd0 = (tid & 7) * 8;

  for (int mt = 0; mt < Ntok / 32; ++mt) {
    int m0 = mt * 32;
    __syncthreads();
    {
      int r = tid >> 3, c8 = (tid & 7) * 8;
      u16x8 tk = *reinterpret_cast<const u16x8*>(&kg[(size_t)(m0 + r) * D + c8]);
      u16x8 tv = *reinterpret_cast<const u16x8*>(&vg[(size_t)(m0 + r) * D + c8]);
#pragma unroll
      for (int e = 0; e < 8; ++e) { ks[r][c8 + e] = bf2f(tk[e]); vs[r][c8 + e] = bf2f(tv[e]); }
    }
    __syncthreads();
    {
      int np = tid >> 3;
      int mp0 = (tid & 7) * 4;
      float s0 = 0.f, s1 = 0.f, s2 = 0.f, s3 = 0.f;
#pragma unroll 8
      for (int d = 0; d < 64; ++d) {
        float qv = qs[np][d];
        s0 = fmaf(qv, ks[mp0 + 0][d], s0);
        s1 = fmaf(qv, ks[mp0 + 1][d], s1);
        s2 = fmaf(qv, ks[mp0 + 2][d], s2);
        s3 = fmaf(qv, ks[mp0 + 3][d], s3);
      }
      Ss[np][mp0 + 0] = s0; Ss[np][mp0 + 1] = s1;
      Ss[np][mp0 + 2] = s2; Ss[np][mp0 + 3] = s3;
    }
    __syncthreads();
#pragma unroll 8
    for (int mp = 0; mp < 32; ++mp) {
      float sv = Ss[nloc][mp];
#pragma unroll
      for (int j = 0; j < 8; ++j) acc[j] = fmaf(sv, vs[mp][dd0 + j], acc[j]);
    }
  }

#pragma unroll
  for (int j = 0; j < 8; ++j) {
    float x = scale * acc[j];
    unsigned short sp = (x >= 1.0f) ? 0x3F80 : 0;
    outbase[(size_t)nloc * 2048 + dd0 + j] = sp;
    outbase[(size_t)nloc * 2048 + 1024 + dd0 + j] = sp;
  }
}

// ======================================================================
extern "C" void kernel_launch(void* const* d_in, const int* in_sizes, int n_in,
                              void* d_out, int out_size, void* d_ws, size_t ws_size,
                              hipStream_t stream)
{
  (void)in_sizes; (void)n_in; (void)out_size; (void)ws_size;
  const int Ntok = 1024, D = 1024;
  const int M = 4096;
  const float scale = 0.5946035575013605f;      // 64^(-1/8)

  const float* x     = (const float*)d_in[0];
  const float* Wq    = (const float*)d_in[1];
  const float* bq    = (const float*)d_in[2];
  const float* gq    = (const float*)d_in[3];
  const float* betaq = (const float*)d_in[4];
  const float* Wk    = (const float*)d_in[5];
  const float* bk    = (const float*)d_in[6];
  const float* gk    = (const float*)d_in[7];
  const float* betak = (const float*)d_in[8];
  const float* Wv    = (const float*)d_in[9];
  const float* bv    = (const float*)d_in[10];
  const float* gv    = (const float*)d_in[11];
  const float* betav = (const float*)d_in[12];
  const float* Wp    = (const float*)d_in[13];
  const float* bp    = (const float*)d_in[14];
  const float* gp    = (const float*)d_in[15];
  const float* betap = (const float*)d_in[16];
  const float* Wg    = (const float*)d_in[17];
  const float* bg    = (const float*)d_in[18];

  char* w = (char*)d_ws;
  const size_t MB = 1024 * 1024;
  const size_t MN = (size_t)M * D;
  unsigned short* Y3bf  = (unsigned short*)(w + 0 * MB);    // q,k,v pre-activations (24 MB)
  unsigned short* xat2  = (unsigned short*)(w + 0 * MB);    // alias 16 MB (q,k slots dead)
  unsigned short* Yv    = Y3bf + 2 * MN;                    // v slot (survives alias)
  unsigned short* Yp    = (unsigned short*)(w + 24 * MB);   // 8 MB
  unsigned short* Wpcat = (unsigned short*)(w + 32 * MB);   // 4 MB
  unsigned short* Xh    = (unsigned short*)(w + 48 * MB);   // 8 MB
  unsigned short* Wh3   = (unsigned short*)(w + 56 * MB);   // 6 MB
  unsigned short* qb2   = (unsigned short*)(w + 62 * MB);   // 8 MB
  unsigned short* kb2   = (unsigned short*)(w + 70 * MB);   // 8 MB
  unsigned short* vb2   = (unsigned short*)(w + 78 * MB);   // 8 MB
  double* psum   = (double*)(w + 86 * MB);                  // 768 KB
  double* psq    = (double*)(w + 87 * MB);                  // 768 KB
  float*  meanv  = (float*)(w + 88 * MB);
  float*  Av     = (float*)(w + 88 * MB + 16384);
  int*    energy_int = (int*)(w + 88 * MB + 32768);         // 64 ints
  int*    flags  = (int*)(w + 88 * MB + 32768 + 512);       // [any, batch0..3]
  float*  gate   = (float*)(w + 88 * MB + 32768 + 1024);    // 64 floats

  float* out = (float*)d_out;
  unsigned short* Whq = Wh3;
  unsigned short* Whk = Wh3 + MN / 4;       // 1024*1024
  unsigned short* Whv = Wh3 + MN / 2;

  // ---- converts (always-needed part) ----
  prep1_kernel<<<dim3(3072), 256, 0, stream>>>(x, Wq, Wk, Xh, Wh3);

  // ---- q,k GEMM (+fused stats) ----
  gemm_bf16_bt<0><<<dim3(8, 32, 2), 256, 0, stream>>>(
      Xh, Whq, Whk, bq, bk, Y3bf, psum, psq, nullptr, D, 1024);
  bn_finalize<<<dim3(4, 2), 256, 0, stream>>>(
      psum, psq, gq, gk, meanv, Av, nullptr, flags, energy_int, D, 1.0 / M);
  spike_qk_energy<<<dim3(512), 256, 0, stream>>>(
      Y3bf, Y3bf + MN, meanv, Av, betaq, betak, qb2, kb2, energy_int, D);

  // ---- gate ----
  gate_kernel<<<dim3(64), 256, 0, stream>>>(energy_int, Wg, bg, gate, flags, D);

  // ---- deferred converts (only if some gate fired) ----
  prep2_kernel<<<dim3(1024), 256, 0, stream>>>(Wv, Wp, Whv, Wpcat, flags);

  // ---- v branch (fully skipped when no gate fires) ----
  gemm_bf16_bt<2><<<dim3(8, 32, 1), 256, 0, stream>>>(
      Xh, Whv, Whv, bv, bv, Yv, psum + 2 * 32 * (size_t)D, psq + 2 * 32 * (size_t)D,
      flags, D, 1024);
  bn_finalize<<<dim3(4, 1), 256, 0, stream>>>(
      psum + 2 * 32 * (size_t)D, psq + 2 * 32 * (size_t)D, gv, gv,
      meanv + 2 * D, Av + 2 * D, flags, nullptr, nullptr, D, 1.0 / M);
  spike_v<<<dim3(2048), 256, 0, stream>>>(Yv, meanv + 2 * D, Av + 2 * D, betav, vb2, flags, D);

  // ---- gated attention + spike -> xat2 ([s|s] bf16) ----
  attn_kernel<<<dim3(64, Ntok / 32), 256, 0, stream>>>(
      qb2, kb2, vb2, gate, flags, xat2, Ntok, D, scale);

  // ---- p branch: A=[s|s], B=[Wp_hi|Wp_lo], K=2048; per-batch skip ----
  gemm_bf16_bt<1><<<dim3(8, 32, 1), 256, 0, stream>>>(
      xat2, Wpcat, Wpcat, bp, bp, Yp, psum, psq, flags, D, 2048);
  bn_finalize<<<dim3(4, 1), 256, 0, stream>>>(
      psum, psq, gp, gp, meanv, Av, nullptr, nullptr, nullptr, D, 1.0 / M);
  bn_spike_f32<<<dim3(2048), 256, 0, stream>>>(Yp, meanv, Av, betap, out, D);
}